// Round 4
// baseline (1545.132 us; speedup 1.0000x reference)
//
#include <hip/hip_runtime.h>

#define NN    100000
#define NE    1600000
#define DD    128
#define NB    64                      // nodes per bin
#define NBINS ((NN + NB - 1) / NB)    // 1563
#define ECAP  1280                    // mean 1024, sigma 32 -> +8 sigma
#define S1    132                     // fp32 words per acc/fstage row (16B-aligned)
#define S2    136                     // u16 halves per h1-stage row

typedef float  f4v __attribute__((ext_vector_type(4)));
typedef short  s8v __attribute__((ext_vector_type(8)));
typedef unsigned short u16;
typedef unsigned int   u32;

// fp32 -> bf16 RNE
static __device__ __forceinline__ u16 f2bf(float f) {
    u32 u = __float_as_uint(f);
    return (u16)((u + 0x7fffu + ((u >> 16) & 1u)) >> 16);
}
// unpack packed bf16 pair (low = col l, high = col l+64)
static __device__ __forceinline__ float blo(u32 p) { return __uint_as_float(p << 16); }
static __device__ __forceinline__ float bhi(u32 p) { return __uint_as_float(p & 0xffff0000u); }

// ---------------------------------------------------------------------------
// One prep kernel, three roles by blockIdx:
//  [0,25000):   x[100000][128] f32 -> xbp[100000][64] packed bf16 (cols l,l+64)
//  [25000,25008): W1/W2 -> bf16 B-fragment images (proven in R3)
//  [25008,25015): zero bin counters
// ---------------------------------------------------------------------------
__global__ __launch_bounds__(256) void prep_cvt(
    const float* __restrict__ x,
    const float* __restrict__ W1, const float* __restrict__ W2,
    u32* __restrict__ xbp, u16* __restrict__ img1, u16* __restrict__ img2,
    int* __restrict__ cnt)
{
    const int b   = blockIdx.x;
    const int tid = threadIdx.x;
    if (b < 25000) {
        const int row  = b * 4 + (tid >> 6);
        const int lane = tid & 63;
        const float* xp = x + (size_t)row * DD;
        const float v0 = xp[lane];
        const float v1 = xp[lane + 64];
        xbp[(size_t)row * 64 + lane] = (u32)f2bf(v0) | ((u32)f2bf(v1) << 16);
    } else if (b < 25008) {
        const int gid  = (b - 25000) * 256 + tid;    // 0..2047
        const int frag = gid >> 6;                   // nt*4 + kc
        const int lane = gid & 63;
        const int n  = (frag >> 2) * 16 + (lane & 15);
        const int k0 = (frag & 3) * 32 + (lane >> 4) * 8;
        u16* o1 = img1 + (size_t)gid * 8;
        u16* o2 = img2 + (size_t)gid * 8;
#pragma unroll
        for (int j = 0; j < 8; ++j) {
            o1[j] = f2bf(W1[(size_t)(k0 + j) * DD + n]);
            o2[j] = f2bf(W2[(size_t)(k0 + j) * DD + n]);
        }
    } else {
        const int i = (b - 25008) * 256 + tid;
        if (i < NBINS) cnt[i] = 0;
    }
}

// ---------------------------------------------------------------------------
// Bin edges by destination block: 1563 bins of 64 nodes. Write front is only
// ~1563 active cache lines (L2-resident) -> lines fill before writeback.
// ---------------------------------------------------------------------------
__global__ __launch_bounds__(256) void fill_kernel(
    const int* __restrict__ ei, int* __restrict__ cnt, int2* __restrict__ bins)
{
    const int e = blockIdx.x * 256 + threadIdx.x;
    const int s = ei[e];
    const int d = ei[NE + e];
    const int bin = d >> 6;
    const int pos = atomicAdd(&cnt[bin], 1);
    if (pos < ECAP) bins[(size_t)bin * ECAP + pos] = make_int2(s, d & (NB - 1));
}

// ---------------------------------------------------------------------------
// Fused gather + MLP. One block per bin (64 nodes).
//  phase 0: acc[r][:] = (1+eps)*xbp[node]           (LDS fp32, stride S1)
//  phase 1: per edge, one wave: acc[dst_local][:] += xbp[src]  (ds_add_f32,
//           lane adds words l and l+64 -> 2-way bank aliasing = free)
//  phase 2: per wave (16 rows): A-frags from LDS acc -> MFMA W1 -> bias/ReLU
//           -> bf16 restage (overlaid on own acc slice) -> MFMA W2 -> bias
//           -> f32 transpose stage -> coalesced float4 stores. h never in HBM.
// ---------------------------------------------------------------------------
__global__ __launch_bounds__(256) void mega_kernel(
    const u32* __restrict__ xbp, const int* __restrict__ cnt,
    const int2* __restrict__ bins,
    const u16* __restrict__ img1, const u16* __restrict__ img2,
    const float* __restrict__ b1, const float* __restrict__ b2,
    const float* __restrict__ epsp,
    float* __restrict__ out)
{
    __shared__ float acc[NB * S1];          // 33792 B -> 4 blocks/CU

    const int bin  = blockIdx.x;
    const int wave = threadIdx.x >> 6;
    const int lane = threadIdx.x & 63;
    const int l15  = lane & 15;
    const int quad = lane >> 4;
    const float sc = 1.0f + epsp[0];

    // ---- phase 0: init with self term ----
#pragma unroll 4
    for (int i = 0; i < 16; ++i) {
        const int r = wave * 16 + i;
        const int node = bin * NB + r;
        float v0 = 0.f, v1 = 0.f;
        if (node < NN) {
            const u32 p = xbp[(size_t)node * 64 + lane];
            v0 = sc * blo(p); v1 = sc * bhi(p);
        }
        acc[r * S1 + lane]      = v0;
        acc[r * S1 + lane + 64] = v1;
    }
    __syncthreads();

    // ---- phase 1: edge accumulation ----
    const int count = min(cnt[bin], ECAP);
    const int2* bp = bins + (size_t)bin * ECAP;
    int e = wave;
    for (; e + 4 < count; e += 8) {          // 2 edges in flight per wave
        const int2 e0 = bp[e];
        const int2 e1 = bp[e + 4];
        const u32 p0 = xbp[(size_t)e0.x * 64 + lane];
        const u32 p1 = xbp[(size_t)e1.x * 64 + lane];
        unsafeAtomicAdd(&acc[e0.y * S1 + lane],      blo(p0));
        unsafeAtomicAdd(&acc[e0.y * S1 + lane + 64], bhi(p0));
        unsafeAtomicAdd(&acc[e1.y * S1 + lane],      blo(p1));
        unsafeAtomicAdd(&acc[e1.y * S1 + lane + 64], bhi(p1));
    }
    if (e < count) {
        const int2 e0 = bp[e];
        const u32 p0 = xbp[(size_t)e0.x * 64 + lane];
        unsafeAtomicAdd(&acc[e0.y * S1 + lane],      blo(p0));
        unsafeAtomicAdd(&acc[e0.y * S1 + lane + 64], bhi(p0));
    }
    __syncthreads();

    // ---- phase 2: MLP on this wave's 16 rows ----
    float* slice = acc + wave * 16 * S1;     // wave-private 8448 B region

    // bias fragments (col = nt*16 + l15)
    float bv1[8], bv2[8];
#pragma unroll
    for (int nt = 0; nt < 8; ++nt) {
        bv1[nt] = b1[nt * 16 + l15];
        bv2[nt] = b2[nt * 16 + l15];
    }

    // A-frags from LDS acc (fp32 -> bf16)
    s8v afrag[4];
#pragma unroll
    for (int kc = 0; kc < 4; ++kc) {
        const float* ap = slice + l15 * S1 + kc * 32 + quad * 8;
        const f4v v0 = *(const f4v*)ap;
        const f4v v1 = *(const f4v*)(ap + 4);
        s8v a;
#pragma unroll
        for (int j = 0; j < 4; ++j) { a[j] = (short)f2bf(v0[j]); a[4 + j] = (short)f2bf(v1[j]); }
        afrag[kc] = a;
    }
    __syncthreads();   // all fp32 acc reads done before u16 overlay writes

    f4v acc1[8] = {};
#pragma unroll
    for (int kc = 0; kc < 4; ++kc)
#pragma unroll
        for (int nt = 0; nt < 8; ++nt) {
            const s8v bfr = *(const s8v*)(img1 + ((size_t)((nt * 4 + kc) * 64 + lane)) * 8);
            acc1[nt] = __builtin_amdgcn_mfma_f32_16x16x32_bf16(afrag[kc], bfr, acc1[nt], 0, 0, 0);
        }

    // bias + ReLU -> bf16 restage in own slice (C/D layout -> A layout)
    u16* hst = (u16*)slice;
#pragma unroll
    for (int nt = 0; nt < 8; ++nt)
#pragma unroll
        for (int r = 0; r < 4; ++r) {
            const float v = fmaxf(acc1[nt][r] + bv1[nt], 0.0f);
            hst[(quad * 4 + r) * S2 + nt * 16 + l15] = f2bf(v);
        }

    s8v a2[4];
#pragma unroll
    for (int kc = 0; kc < 4; ++kc)
        a2[kc] = *(const s8v*)&hst[l15 * S2 + kc * 32 + quad * 8];
    __syncthreads();   // u16 phase done before fp32 fstage overlay

    f4v acc2[8] = {};
#pragma unroll
    for (int kc = 0; kc < 4; ++kc)
#pragma unroll
        for (int nt = 0; nt < 8; ++nt) {
            const s8v bfr = *(const s8v*)(img2 + ((size_t)((nt * 4 + kc) * 64 + lane)) * 8);
            acc2[nt] = __builtin_amdgcn_mfma_f32_16x16x32_bf16(a2[kc], bfr, acc2[nt], 0, 0, 0);
        }

    // bias -> fp32 transpose stage -> coalesced stores
#pragma unroll
    for (int nt = 0; nt < 8; ++nt)
#pragma unroll
        for (int r = 0; r < 4; ++r)
            slice[(quad * 4 + r) * S1 + nt * 16 + l15] = acc2[nt][r] + bv2[nt];

#pragma unroll
    for (int i = 0; i < 8; ++i) {
        const int m  = (lane >> 5) + 2 * i;
        const int c4 = lane & 31;
        const f4v v = *(const f4v*)&slice[m * S1 + c4 * 4];
        const int node = bin * NB + wave * 16 + m;
        if (node < NN)
            *(f4v*)(out + (size_t)node * DD + c4 * 4) = v;
    }
}

// ---------------------------------------------------------------------------
extern "C" void kernel_launch(void* const* d_in, const int* in_sizes, int n_in,
                              void* d_out, int out_size, void* d_ws, size_t ws_size,
                              hipStream_t stream) {
    const float* x   = (const float*)d_in[0];
    const int*   ei  = (const int*)d_in[1];
    const float* W1  = (const float*)d_in[2];
    const float* b1  = (const float*)d_in[3];
    const float* W2  = (const float*)d_in[4];
    const float* b2  = (const float*)d_in[5];
    const float* eps = (const float*)d_in[6];
    float* out = (float*)d_out;

    // workspace: xbp 25.6MB | bins 16.0MB | img1 32KB | img2 32KB | cnt 6.3KB
    u32*  xbp  = (u32*)d_ws;
    int2* bins = (int2*)(xbp + (size_t)NN * 64);
    u16*  img1 = (u16*)(bins + (size_t)NBINS * ECAP);
    u16*  img2 = img1 + (size_t)DD * DD;
    int*  cnt  = (int*)(img2 + (size_t)DD * DD);

    prep_cvt   <<<25015,   256, 0, stream>>>(x, W1, W2, xbp, img1, img2, cnt);
    fill_kernel<<<NE / 256, 256, 0, stream>>>(ei, cnt, bins);
    mega_kernel<<<NBINS,    256, 0, stream>>>(xbp, cnt, bins, img1, img2, b1, b2, eps, out);
}

// Round 5
// 360.516 us; speedup vs baseline: 4.2859x; 4.2859x over previous
//
#include <hip/hip_runtime.h>

#define NN    100000
#define NE    1600000
#define DD    128
#define NB    32                      // nodes per dst-bin
#define NBINS (NN / NB)               // 3125 (exact)
#define ECAP  768                     // mean 512, sigma ~22.6 -> +11 sigma
#define CAP   96                      // per-node list cap; Poisson(16) tail ~0

typedef float  f4v __attribute__((ext_vector_type(4)));
typedef short  s8v __attribute__((ext_vector_type(8)));
typedef unsigned short u16;
typedef unsigned int   u32;

// fp32 -> bf16 RNE
static __device__ __forceinline__ u16 f2bf(float f) {
    u32 u = __float_as_uint(f);
    return (u16)((u + 0x7fffu + ((u >> 16) & 1u)) >> 16);
}
// unpack packed bf16 pair (low = col l, high = col l+64)
static __device__ __forceinline__ float blo(u32 p) { return __uint_as_float(p << 16); }
static __device__ __forceinline__ float bhi(u32 p) { return __uint_as_float(p & 0xffff0000u); }

// ---------------------------------------------------------------------------
// prep: three roles by blockIdx
//  [0,25000):      x f32 -> xbp packed bf16 (lane holds cols l, l+64)
//  [25000,25008):  W1/W2 -> bf16 B-fragment images (layout proven R3/R4)
//  [25008,25021):  zero the 3125 bin counters
// ---------------------------------------------------------------------------
__global__ __launch_bounds__(256) void prep_cvt(
    const float* __restrict__ x,
    const float* __restrict__ W1, const float* __restrict__ W2,
    u32* __restrict__ xbp, u16* __restrict__ img1, u16* __restrict__ img2,
    int* __restrict__ cnt)
{
    const int b   = blockIdx.x;
    const int tid = threadIdx.x;
    if (b < 25000) {
        const int row  = b * 4 + (tid >> 6);
        const int lane = tid & 63;
        const float* xp = x + (size_t)row * DD;
        xbp[(size_t)row * 64 + lane] =
            (u32)f2bf(xp[lane]) | ((u32)f2bf(xp[lane + 64]) << 16);
    } else if (b < 25008) {
        const int gid  = (b - 25000) * 256 + tid;    // 0..2047
        const int frag = gid >> 6;                   // nt*4 + kc
        const int lane = gid & 63;
        const int n  = (frag >> 2) * 16 + (lane & 15);
        const int k0 = (frag & 3) * 32 + (lane >> 4) * 8;
        u16* o1 = img1 + (size_t)gid * 8;
        u16* o2 = img2 + (size_t)gid * 8;
#pragma unroll
        for (int j = 0; j < 8; ++j) {
            o1[j] = f2bf(W1[(size_t)(k0 + j) * DD + n]);
            o2[j] = f2bf(W2[(size_t)(k0 + j) * DD + n]);
        }
    } else {
        const int i = (b - 25008) * 256 + tid;
        if (i < NBINS) cnt[i] = 0;
    }
}

// ---------------------------------------------------------------------------
// fill: bin edges by 32-node dst block. Entry packs (src<<5)|dst_local in 22
// bits. Write front = 3125 active lines (~200KB, L2-resident) -> full lines.
// ---------------------------------------------------------------------------
__global__ __launch_bounds__(256) void fill_kernel(
    const int* __restrict__ ei, int* __restrict__ cnt, u32* __restrict__ bins)
{
    const int e = blockIdx.x * 256 + threadIdx.x;
    const int s = ei[e];
    const int d = ei[NE + e];
    const int bin = d >> 5;
    const int pos = atomicAdd(&cnt[bin], 1);
    if (pos < ECAP) bins[(size_t)bin * ECAP + pos] = ((u32)s << 5) | (u32)(d & 31);
}

// ---------------------------------------------------------------------------
// b2l: one block per bin; bucket ~512 entries into per-node lists via LDS int
// counters. Each block's writes land in its own 32*CAP*4 = 12KB region.
// ---------------------------------------------------------------------------
__global__ __launch_bounds__(256) void b2l_kernel(
    const int* __restrict__ cnt, const u32* __restrict__ bins,
    int* __restrict__ eidx, int* __restrict__ degs)
{
    __shared__ int lcnt[NB];
    const int bin = blockIdx.x;
    const int tid = threadIdx.x;
    if (tid < NB) lcnt[tid] = 0;
    __syncthreads();
    const int n = min(cnt[bin], ECAP);
    const u32* bp = bins + (size_t)bin * ECAP;
    for (int i = tid; i < n; i += 256) {
        const u32 v  = bp[i];
        const int dl = (int)(v & 31);
        const int pos = atomicAdd(&lcnt[dl], 1);
        if (pos < CAP) eidx[(size_t)(bin * NB + dl) * CAP + pos] = (int)(v >> 5);
    }
    __syncthreads();
    if (tid < NB) degs[bin * NB + tid] = min(lcnt[tid], CAP);
}

// ---------------------------------------------------------------------------
// gather: one wave per node (100k waves — max parallelism, 4 loads in flight).
// Reads packed-bf16 xbp rows (256B/row, 25.6MB working set, L3-resident).
// Writes hb[node][128] bf16 row-major == MFMA A-fragment-friendly layout.
// ---------------------------------------------------------------------------
__global__ __launch_bounds__(256) void gather_kernel(
    const u32* __restrict__ xbp, const int* __restrict__ degs,
    const int* __restrict__ eidx, const float* __restrict__ epsp,
    u16* __restrict__ hb)
{
    const int node = blockIdx.x * 4 + (threadIdx.x >> 6);
    const int lane = threadIdx.x & 63;
    const int deg  = degs[node];
    const int base = node * CAP;

    float a0 = 0.f, a1 = 0.f, a2 = 0.f, a3 = 0.f;
    float c0 = 0.f, c1 = 0.f, c2 = 0.f, c3 = 0.f;

    int j = 0;
    for (; j + 4 <= deg; j += 4) {
        const int s0 = eidx[base + j];
        const int s1 = eidx[base + j + 1];
        const int s2 = eidx[base + j + 2];
        const int s3 = eidx[base + j + 3];
        const u32 p0 = xbp[(size_t)s0 * 64 + lane];
        const u32 p1 = xbp[(size_t)s1 * 64 + lane];
        const u32 p2 = xbp[(size_t)s2 * 64 + lane];
        const u32 p3 = xbp[(size_t)s3 * 64 + lane];
        a0 += blo(p0); c0 += bhi(p0);
        a1 += blo(p1); c1 += bhi(p1);
        a2 += blo(p2); c2 += bhi(p2);
        a3 += blo(p3); c3 += bhi(p3);
    }
    for (; j < deg; ++j) {
        const int s0 = eidx[base + j];
        const u32 p0 = xbp[(size_t)s0 * 64 + lane];
        a0 += blo(p0); c0 += bhi(p0);
    }

    const float sc = 1.0f + epsp[0];
    const u32 ps = xbp[(size_t)node * 64 + lane];
    const float r0 = sc * blo(ps) + (a0 + a1) + (a2 + a3);
    const float r1 = sc * bhi(ps) + (c0 + c1) + (c2 + c3);
    hb[(size_t)node * DD + lane]      = f2bf(r0);
    hb[(size_t)node * DD + lane + 64] = f2bf(r1);
}

// ---------------------------------------------------------------------------
// mlp: R3-proven fused MLP; A-frags now load directly from bf16 hb (no cvt).
// 4 waves/block, wave owns 16 rows end-to-end; hidden layer restaged through
// wave-private LDS; tail waves clamp rbase (duplicate identical stores).
// ---------------------------------------------------------------------------
__global__ __launch_bounds__(256) void mlp_kernel(
    const u16* __restrict__ hb,
    const u16* __restrict__ img1, const u16* __restrict__ img2,
    const float* __restrict__ b1, const float* __restrict__ b2,
    float* __restrict__ out)
{
    __shared__ char lds_raw[4 * 8448];
    const int tid  = threadIdx.x;
    const int wave = tid >> 6;
    const int lane = tid & 63;
    const int l15  = lane & 15;
    const int quad = lane >> 4;

    float* fstage = (float*)(lds_raw + wave * 8448);   // stride 132 f32
    u16*   hstage = (u16*)fstage;                      // stride 136 u16

    int rbase = (blockIdx.x * 4 + wave) * 16;
    if (rbase > NN - 16) rbase = NN - 16;

    float bv1[8], bv2[8];
#pragma unroll
    for (int nt = 0; nt < 8; ++nt) {
        bv1[nt] = b1[nt * 16 + l15];
        bv2[nt] = b2[nt * 16 + l15];
    }

    // layer 1: A-frags straight from hb (already A-layout bf16)
    s8v afrag[4];
#pragma unroll
    for (int kc = 0; kc < 4; ++kc)
        afrag[kc] = *(const s8v*)(hb + (size_t)(rbase + l15) * DD + kc * 32 + quad * 8);

    f4v acc1[8] = {};
#pragma unroll
    for (int kc = 0; kc < 4; ++kc)
#pragma unroll
        for (int nt = 0; nt < 8; ++nt) {
            const s8v bfr = *(const s8v*)(img1 + ((size_t)((nt * 4 + kc) * 64 + lane)) * 8);
            acc1[nt] = __builtin_amdgcn_mfma_f32_16x16x32_bf16(afrag[kc], bfr, acc1[nt], 0, 0, 0);
        }

    // bias + ReLU -> bf16 restage (C/D layout -> A layout)
#pragma unroll
    for (int nt = 0; nt < 8; ++nt)
#pragma unroll
        for (int r = 0; r < 4; ++r) {
            const float v = fmaxf(acc1[nt][r] + bv1[nt], 0.0f);
            hstage[(quad * 4 + r) * 136 + nt * 16 + l15] = f2bf(v);
        }
    __syncthreads();

    s8v a2[4];
#pragma unroll
    for (int kc = 0; kc < 4; ++kc)
        a2[kc] = *(const s8v*)&hstage[l15 * 136 + kc * 32 + quad * 8];

    f4v acc2[8] = {};
#pragma unroll
    for (int kc = 0; kc < 4; ++kc)
#pragma unroll
        for (int nt = 0; nt < 8; ++nt) {
            const s8v bfr = *(const s8v*)(img2 + ((size_t)((nt * 4 + kc) * 64 + lane)) * 8);
            acc2[nt] = __builtin_amdgcn_mfma_f32_16x16x32_bf16(a2[kc], bfr, acc2[nt], 0, 0, 0);
        }

    __syncthreads();   // a2 reads done before fp32 overlay
#pragma unroll
    for (int nt = 0; nt < 8; ++nt)
#pragma unroll
        for (int r = 0; r < 4; ++r)
            fstage[(quad * 4 + r) * 132 + nt * 16 + l15] = acc2[nt][r] + bv2[nt];
    __syncthreads();

#pragma unroll
    for (int i = 0; i < 8; ++i) {
        const int m  = (lane >> 5) + 2 * i;
        const int c4 = lane & 31;
        const f4v v = *(const f4v*)&fstage[m * 132 + c4 * 4];
        *(f4v*)(out + (size_t)(rbase + m) * DD + c4 * 4) = v;
    }
}

// ---------------------------------------------------------------------------
extern "C" void kernel_launch(void* const* d_in, const int* in_sizes, int n_in,
                              void* d_out, int out_size, void* d_ws, size_t ws_size,
                              hipStream_t stream) {
    const float* x   = (const float*)d_in[0];
    const int*   ei  = (const int*)d_in[1];
    const float* W1  = (const float*)d_in[2];
    const float* b1  = (const float*)d_in[3];
    const float* W2  = (const float*)d_in[4];
    const float* b2  = (const float*)d_in[5];
    const float* eps = (const float*)d_in[6];
    float* out = (float*)d_out;

    // workspace: xbp 25.6 | hb 25.6 | eidx 38.4 | bins 9.6 | degs 0.4 | imgs/cnt
    // total ~99.7 MB (<= 102.4 MB proven in R1)
    u32* xbp  = (u32*)d_ws;
    u16* hb   = (u16*)(xbp + (size_t)NN * 64);
    int* eidx = (int*)(hb + (size_t)NN * DD);
    u32* bins = (u32*)(eidx + (size_t)NN * CAP);
    int* degs = (int*)(bins + (size_t)NBINS * ECAP);
    u16* img1 = (u16*)(degs + NN);
    u16* img2 = img1 + (size_t)DD * DD;
    int* cnt  = (int*)(img2 + (size_t)DD * DD);

    prep_cvt     <<<25021,    256, 0, stream>>>(x, W1, W2, xbp, img1, img2, cnt);
    fill_kernel  <<<NE / 256, 256, 0, stream>>>(ei, cnt, bins);
    b2l_kernel   <<<NBINS,    256, 0, stream>>>(cnt, bins, eidx, degs);
    gather_kernel<<<NN / 4,   256, 0, stream>>>(xbp, degs, eidx, eps, hb);
    mlp_kernel   <<<(NN / 16 + 3) / 4, 256, 0, stream>>>(hb, img1, img2, b1, b2, out);
}

// Round 6
// 346.142 us; speedup vs baseline: 4.4639x; 1.0415x over previous
//
#include <hip/hip_runtime.h>

#define NN    100000
#define NE    1600000
#define DD    128
#define CAP   96    // per-node list cap; deg ~ Poisson(16), P(deg>96) ~ 0

typedef float  f4v __attribute__((ext_vector_type(4)));
typedef short  s8v __attribute__((ext_vector_type(8)));
typedef unsigned short u16;
typedef unsigned int   u32;

// fp32 -> bf16 RNE
static __device__ __forceinline__ u16 f2bf(float f) {
    u32 u = __float_as_uint(f);
    return (u16)((u + 0x7fffu + ((u >> 16) & 1u)) >> 16);
}
// unpack packed bf16 pair (low = col l, high = col l+64)
static __device__ __forceinline__ float blo(u32 p) { return __uint_as_float(p << 16); }
static __device__ __forceinline__ float bhi(u32 p) { return __uint_as_float(p & 0xffff0000u); }

// ---------------------------------------------------------------------------
// prep: three roles by blockIdx
//  [0,25000):      x f32 -> xbp packed bf16 (lane holds cols l, l+64)
//  [25000,25008):  W1/W2 -> bf16 B-fragment images (layout proven R3-R5)
//  [25008,25399):  zero the 100k per-node edge counters
// ---------------------------------------------------------------------------
__global__ __launch_bounds__(256) void prep_cvt(
    const float* __restrict__ x,
    const float* __restrict__ W1, const float* __restrict__ W2,
    u32* __restrict__ xbp, u16* __restrict__ img1, u16* __restrict__ img2,
    int* __restrict__ cnt)
{
    const int b   = blockIdx.x;
    const int tid = threadIdx.x;
    if (b < 25000) {
        const int row  = b * 4 + (tid >> 6);
        const int lane = tid & 63;
        const float* xp = x + (size_t)row * DD;
        xbp[(size_t)row * 64 + lane] =
            (u32)f2bf(xp[lane]) | ((u32)f2bf(xp[lane + 64]) << 16);
    } else if (b < 25008) {
        const int gid  = (b - 25000) * 256 + tid;    // 0..2047
        const int frag = gid >> 6;                   // nt*4 + kc
        const int lane = gid & 63;
        const int n  = (frag >> 2) * 16 + (lane & 15);
        const int k0 = (frag & 3) * 32 + (lane >> 4) * 8;
        u16* o1 = img1 + (size_t)gid * 8;
        u16* o2 = img2 + (size_t)gid * 8;
#pragma unroll
        for (int j = 0; j < 8; ++j) {
            o1[j] = f2bf(W1[(size_t)(k0 + j) * DD + n]);
            o2[j] = f2bf(W2[(size_t)(k0 + j) * DD + n]);
        }
    } else {
        const int i = (b - 25008) * 256 + tid;
        if (i < NN) cnt[i] = 0;
    }
}

// ---------------------------------------------------------------------------
// fill: direct per-node edge lists. BOTH the slot reservation (atomicAdd) and
// the payload store (fire-and-forget atomicExch) are device-scope atomics ->
// they execute at the die-shared memory side, so a list line dirtied by
// blocks on all 8 XCDs accumulates ONCE instead of 8 partial-line writebacks
// (R5 measured 8x WRITE amplification with plain stores).
// ---------------------------------------------------------------------------
__global__ __launch_bounds__(256) void fill_kernel(
    const int* __restrict__ ei, int* __restrict__ cnt, int* __restrict__ eidx)
{
    const int e = blockIdx.x * 256 + threadIdx.x;
    const int s = ei[e];
    const int d = ei[NE + e];
    const int pos = atomicAdd(&cnt[d], 1);
    if (pos < CAP) atomicExch(&eidx[(size_t)d * CAP + pos], s);
}

// ---------------------------------------------------------------------------
// gather: one wave per node (100k waves). Reads packed-bf16 xbp rows (256B,
// 25.6MB working set -> L3-resident). 8 row-loads in flight. Writes bf16
// hb[node][128] row-major == MFMA A-fragment layout.
// ---------------------------------------------------------------------------
__global__ __launch_bounds__(256) void gather_kernel(
    const u32* __restrict__ xbp, const int* __restrict__ cnt,
    const int* __restrict__ eidx, const float* __restrict__ epsp,
    u16* __restrict__ hb)
{
    const int node = blockIdx.x * 4 + (threadIdx.x >> 6);
    const int lane = threadIdx.x & 63;
    const int deg  = min(cnt[node], CAP);
    const int base = node * CAP;

    float a[8] = {};   // low-col partials
    float c[8] = {};   // high-col partials

    int j = 0;
    for (; j + 8 <= deg; j += 8) {
        int  si[8];
        u32  pi[8];
#pragma unroll
        for (int t = 0; t < 8; ++t) si[t] = eidx[base + j + t];
#pragma unroll
        for (int t = 0; t < 8; ++t) pi[t] = xbp[(size_t)si[t] * 64 + lane];
#pragma unroll
        for (int t = 0; t < 8; ++t) { a[t] += blo(pi[t]); c[t] += bhi(pi[t]); }
    }
    if (j + 4 <= deg) {
        int si[4]; u32 pi[4];
#pragma unroll
        for (int t = 0; t < 4; ++t) si[t] = eidx[base + j + t];
#pragma unroll
        for (int t = 0; t < 4; ++t) pi[t] = xbp[(size_t)si[t] * 64 + lane];
#pragma unroll
        for (int t = 0; t < 4; ++t) { a[t] += blo(pi[t]); c[t] += bhi(pi[t]); }
        j += 4;
    }
    for (; j < deg; ++j) {
        const u32 p = xbp[(size_t)eidx[base + j] * 64 + lane];
        a[0] += blo(p); c[0] += bhi(p);
    }

    const float sc = 1.0f + epsp[0];
    const u32 ps = xbp[(size_t)node * 64 + lane];
    const float r0 = sc * blo(ps) + ((a[0]+a[1]) + (a[2]+a[3])) + ((a[4]+a[5]) + (a[6]+a[7]));
    const float r1 = sc * bhi(ps) + ((c[0]+c[1]) + (c[2]+c[3])) + ((c[4]+c[5]) + (c[6]+c[7]));
    hb[(size_t)node * DD + lane]      = f2bf(r0);
    hb[(size_t)node * DD + lane + 64] = f2bf(r1);
}

// ---------------------------------------------------------------------------
// mlp: fused 2-layer MLP (proven R3/R5). A-frags load directly from bf16 hb;
// hidden layer restaged through wave-private LDS; tail waves clamp rbase.
// ---------------------------------------------------------------------------
__global__ __launch_bounds__(256) void mlp_kernel(
    const u16* __restrict__ hb,
    const u16* __restrict__ img1, const u16* __restrict__ img2,
    const float* __restrict__ b1, const float* __restrict__ b2,
    float* __restrict__ out)
{
    __shared__ char lds_raw[4 * 8448];
    const int tid  = threadIdx.x;
    const int wave = tid >> 6;
    const int lane = tid & 63;
    const int l15  = lane & 15;
    const int quad = lane >> 4;

    float* fstage = (float*)(lds_raw + wave * 8448);   // stride 132 f32
    u16*   hstage = (u16*)fstage;                      // stride 136 u16

    int rbase = (blockIdx.x * 4 + wave) * 16;
    if (rbase > NN - 16) rbase = NN - 16;

    float bv1[8], bv2[8];
#pragma unroll
    for (int nt = 0; nt < 8; ++nt) {
        bv1[nt] = b1[nt * 16 + l15];
        bv2[nt] = b2[nt * 16 + l15];
    }

    s8v afrag[4];
#pragma unroll
    for (int kc = 0; kc < 4; ++kc)
        afrag[kc] = *(const s8v*)(hb + (size_t)(rbase + l15) * DD + kc * 32 + quad * 8);

    f4v acc1[8] = {};
#pragma unroll
    for (int kc = 0; kc < 4; ++kc)
#pragma unroll
        for (int nt = 0; nt < 8; ++nt) {
            const s8v bfr = *(const s8v*)(img1 + ((size_t)((nt * 4 + kc) * 64 + lane)) * 8);
            acc1[nt] = __builtin_amdgcn_mfma_f32_16x16x32_bf16(afrag[kc], bfr, acc1[nt], 0, 0, 0);
        }

#pragma unroll
    for (int nt = 0; nt < 8; ++nt)
#pragma unroll
        for (int r = 0; r < 4; ++r) {
            const float v = fmaxf(acc1[nt][r] + bv1[nt], 0.0f);
            hstage[(quad * 4 + r) * 136 + nt * 16 + l15] = f2bf(v);
        }
    __syncthreads();

    s8v a2[4];
#pragma unroll
    for (int kc = 0; kc < 4; ++kc)
        a2[kc] = *(const s8v*)&hstage[l15 * 136 + kc * 32 + quad * 8];

    f4v acc2[8] = {};
#pragma unroll
    for (int kc = 0; kc < 4; ++kc)
#pragma unroll
        for (int nt = 0; nt < 8; ++nt) {
            const s8v bfr = *(const s8v*)(img2 + ((size_t)((nt * 4 + kc) * 64 + lane)) * 8);
            acc2[nt] = __builtin_amdgcn_mfma_f32_16x16x32_bf16(a2[kc], bfr, acc2[nt], 0, 0, 0);
        }

    __syncthreads();
#pragma unroll
    for (int nt = 0; nt < 8; ++nt)
#pragma unroll
        for (int r = 0; r < 4; ++r)
            fstage[(quad * 4 + r) * 132 + nt * 16 + l15] = acc2[nt][r] + bv2[nt];
    __syncthreads();

#pragma unroll
    for (int i = 0; i < 8; ++i) {
        const int m  = (lane >> 5) + 2 * i;
        const int c4 = lane & 31;
        const f4v v = *(const f4v*)&fstage[m * 132 + c4 * 4];
        *(f4v*)(out + (size_t)(rbase + m) * DD + c4 * 4) = v;
    }
}

// ---------------------------------------------------------------------------
extern "C" void kernel_launch(void* const* d_in, const int* in_sizes, int n_in,
                              void* d_out, int out_size, void* d_ws, size_t ws_size,
                              hipStream_t stream) {
    const float* x   = (const float*)d_in[0];
    const int*   ei  = (const int*)d_in[1];
    const float* W1  = (const float*)d_in[2];
    const float* b1  = (const float*)d_in[3];
    const float* W2  = (const float*)d_in[4];
    const float* b2  = (const float*)d_in[5];
    const float* eps = (const float*)d_in[6];
    float* out = (float*)d_out;

    // workspace: xbp 25.6 | hb 25.6 | eidx 38.4 | cnt 0.4 | imgs 64KB  (~90 MB)
    u32* xbp  = (u32*)d_ws;
    u16* hb   = (u16*)(xbp + (size_t)NN * 64);
    int* eidx = (int*)(hb + (size_t)NN * DD);
    int* cnt  = (int*)(eidx + (size_t)NN * CAP);
    u16* img1 = (u16*)(cnt + NN);
    u16* img2 = img1 + (size_t)DD * DD;

    prep_cvt     <<<25399,    256, 0, stream>>>(x, W1, W2, xbp, img1, img2, cnt);
    fill_kernel  <<<NE / 256, 256, 0, stream>>>(ei, cnt, eidx);
    gather_kernel<<<NN / 4,   256, 0, stream>>>(xbp, cnt, eidx, eps, hb);
    mlp_kernel   <<<(NN / 16 + 3) / 4, 256, 0, stream>>>(hb, img1, img2, b1, b2, out);
}